// Round 1
// baseline (729.391 us; speedup 1.0000x reference)
//
#include <hip/hip_runtime.h>
#include <cstdint>
#include <cstddef>

// Problem: trajectory[b,t,k] = sum_d x0[b,d] * expm(t*dt*A)[k,d]
//   B=4096, T=100, D=256, dt=0.05, t = 0..99
// Strategy:
//   Phase 1 (fp32): M = expm(dt*A) by order-6 Taylor (Horner, 5 matmuls);
//                   E[t] = M^t by doubling levels E[2^j + r] = E[2^j]*E[r].
//   Phase 2 (fp16 MFMA): C[4096 x 25600] = X0 * W^T, W[t*256+k][d] = E[t][k][d]
//                   (E's row-major storage IS W). Output fp32.

#define TSTEPS 100
#define NCOLS  (TSTEPS * 256)   // 25600
#define DT     0.05f

typedef _Float16 half8 __attribute__((ext_vector_type(8)));
typedef _Float16 half4 __attribute__((ext_vector_type(4)));
typedef float    f32x4 __attribute__((ext_vector_type(4)));

// ---------- init: E[0] = I ; R = I + c*A (Horner seed I + X/6) ----------
__global__ void init_kernel(const float* __restrict__ A, float* __restrict__ E0,
                            float* __restrict__ R, float c) {
  int i = blockIdx.x * 256 + threadIdx.x;   // 65536 elements
  float id = ((i >> 8) == (i & 255)) ? 1.f : 0.f;
  E0[i] = id;
  R[i]  = id + c * A[i];
}

// ---------- batched 256x256 fp32 matmul: C_i = alpha*(A*B_i) (+ I) ----------
// grid: (16, cnt); 64x64 tile per block, 256 threads, 4x4 outputs/thread.
__global__ __launch_bounds__(256) void mm256(const float* __restrict__ A,
                                             const float* __restrict__ Bb,
                                             float* __restrict__ Cb,
                                             float alpha, int addI) {
  const float* B = Bb + (size_t)blockIdx.y * 65536;
  float*       C = Cb + (size_t)blockIdx.y * 65536;
  const int tm = (blockIdx.x & 3) * 64;
  const int tn = (blockIdx.x >> 2) * 64;
  __shared__ float As[64][33];   // +1 pad: inner-loop row reads spread banks
  __shared__ float Bs[32][68];   // stride 68 floats = 272 B (16B-aligned rows)
  const int t  = threadIdx.x;
  const int tr = t >> 4, tc = t & 15;
  const int arow = t >> 3, acol = (t & 7) * 4;    // A tile 64x32
  const int brow = t >> 4, bcol = (t & 15) * 4;   // B tile 32x64
  float acc[4][4] = {};
  for (int kk = 0; kk < 256; kk += 32) {
    __syncthreads();
#pragma unroll
    for (int p = 0; p < 2; ++p) {
      int r = arow + p * 32;
      const float4 v = *(const float4*)(A + (size_t)(tm + r) * 256 + kk + acol);
      As[r][acol] = v.x; As[r][acol + 1] = v.y; As[r][acol + 2] = v.z; As[r][acol + 3] = v.w;
    }
#pragma unroll
    for (int p = 0; p < 2; ++p) {
      int r = brow + p * 16;
      const float4 v = *(const float4*)(B + (size_t)(kk + r) * 256 + tn + bcol);
      *(float4*)(&Bs[r][bcol]) = v;
    }
    __syncthreads();
#pragma unroll
    for (int k2 = 0; k2 < 32; ++k2) {
      float a0 = As[tr * 4 + 0][k2];
      float a1 = As[tr * 4 + 1][k2];
      float a2 = As[tr * 4 + 2][k2];
      float a3 = As[tr * 4 + 3][k2];
      const float4 b = *(const float4*)(&Bs[k2][tc * 4]);
      acc[0][0] += a0 * b.x; acc[0][1] += a0 * b.y; acc[0][2] += a0 * b.z; acc[0][3] += a0 * b.w;
      acc[1][0] += a1 * b.x; acc[1][1] += a1 * b.y; acc[1][2] += a1 * b.z; acc[1][3] += a1 * b.w;
      acc[2][0] += a2 * b.x; acc[2][1] += a2 * b.y; acc[2][2] += a2 * b.z; acc[2][3] += a2 * b.w;
      acc[3][0] += a3 * b.x; acc[3][1] += a3 * b.y; acc[3][2] += a3 * b.z; acc[3][3] += a3 * b.w;
    }
  }
#pragma unroll
  for (int i = 0; i < 4; ++i) {
    int m = tm + tr * 4 + i;
#pragma unroll
    for (int j = 0; j < 4; ++j) {
      int n = tn + tc * 4 + j;
      float v = alpha * acc[i][j];
      if (addI && m == n) v += 1.f;
      C[(size_t)m * 256 + n] = v;
    }
  }
}

// ---------- fp32 -> fp16 convert, 4 elems/thread ----------
__global__ void f2h(const float* __restrict__ s, _Float16* __restrict__ d) {
  int i = (blockIdx.x * 256 + threadIdx.x) * 4;
  const float4 v = *(const float4*)(s + i);
  half4 h;
  h[0] = (_Float16)v.x; h[1] = (_Float16)v.y; h[2] = (_Float16)v.z; h[3] = (_Float16)v.w;
  *(half4*)(d + i) = h;
}

// ---------- phase 2: C[4096 x 25600] = X (4096x256) * W^T (25600x256), fp16 MFMA ----------
// 128x128 tile / block, 4 waves, each wave 64x64 (4x4 frags of 16x16x32).
__global__ __launch_bounds__(256) void gemm_out(const _Float16* __restrict__ X,
                                                const _Float16* __restrict__ W,
                                                float* __restrict__ out) {
  const int bt = blockIdx.x & 31;   // M-tile (32) — fastest so consecutive blocks share W tile
  const int nt = blockIdx.x >> 5;   // N-tile (200)
  const int m0 = bt * 128, n0 = nt * 128;
  __shared__ _Float16 As[128 * 72];   // row stride 72 halves = 144 B (16B-aligned, 2-way-max banks)
  __shared__ _Float16 Bs[128 * 72];
  const int t    = threadIdx.x;
  const int srow = t >> 3;            // 0..31 (+p*32): 8 lanes x 16B per 64-half row
  const int scol = (t & 7) * 8;
  const int lane = t & 63, wave = t >> 6;
  const int wm = (wave & 1) * 64, wn = (wave >> 1) * 64;
  const int quad = lane >> 4, l16 = lane & 15;

  f32x4 acc[4][4];
#pragma unroll
  for (int i = 0; i < 4; ++i)
#pragma unroll
    for (int j = 0; j < 4; ++j) acc[i][j] = f32x4{0.f, 0.f, 0.f, 0.f};

  for (int kk = 0; kk < 256; kk += 64) {
    __syncthreads();
#pragma unroll
    for (int p = 0; p < 4; ++p) {
      int r = srow + p * 32;
      *(uint4*)(&As[r * 72 + scol]) = *(const uint4*)(X + (size_t)(m0 + r) * 256 + kk + scol);
      *(uint4*)(&Bs[r * 72 + scol]) = *(const uint4*)(W + (size_t)(n0 + r) * 256 + kk + scol);
    }
    __syncthreads();
#pragma unroll
    for (int ks = 0; ks < 64; ks += 32) {
      half8 af[4], bf[4];
#pragma unroll
      for (int i = 0; i < 4; ++i)
        af[i] = *(const half8*)(&As[(wm + i * 16 + l16) * 72 + ks + quad * 8]);
#pragma unroll
      for (int j = 0; j < 4; ++j)
        bf[j] = *(const half8*)(&Bs[(wn + j * 16 + l16) * 72 + ks + quad * 8]);
#pragma unroll
      for (int i = 0; i < 4; ++i)
#pragma unroll
        for (int j = 0; j < 4; ++j)
          acc[i][j] = __builtin_amdgcn_mfma_f32_16x16x32_f16(af[i], bf[j], acc[i][j], 0, 0, 0);
    }
  }
  // D layout (m89-verified): col = lane&15, row = quad*4 + reg
#pragma unroll
  for (int i = 0; i < 4; ++i)
#pragma unroll
    for (int j = 0; j < 4; ++j) {
      const int col = n0 + wn + j * 16 + l16;
#pragma unroll
      for (int r = 0; r < 4; ++r) {
        const int row = m0 + wm + i * 16 + quad * 4 + r;
        out[(size_t)row * NCOLS + col] = acc[i][j][r];
      }
    }
}

extern "C" void kernel_launch(void* const* d_in, const int* in_sizes, int n_in,
                              void* d_out, int out_size, void* d_ws, size_t ws_size,
                              hipStream_t stream) {
  const float* X0 = (const float*)d_in[0];   // [4096, 256]
  const float* A  = (const float*)d_in[1];   // [256, 256]
  float* out = (float*)d_out;                // [4096, 100, 256]

  // workspace layout (≈40 MB total)
  float* E  = (float*)d_ws;                  // 100 * 65536 fp32 = 26.2 MB; E[t] row-major [k][d]
  float* R0 = E + (size_t)TSTEPS * 65536;    // Horner ping
  float* R1 = R0 + 65536;                    // Horner pong
  _Float16* Xh = (_Float16*)(R1 + 65536);    // 4096*256 fp16 = 2 MB
  _Float16* Wh = Xh + (size_t)4096 * 256;    // 25600*256 fp16 = 13.1 MB

  // ---- Phase 1: E[0] = I, E[1] = expm(dt*A) (order-6 Taylor, Horner) ----
  init_kernel<<<256, 256, 0, stream>>>(A, E, R0, DT / 6.f);
  mm256<<<dim3(16, 1), 256, 0, stream>>>(A, R0, R1, DT / 5.f, 1);
  mm256<<<dim3(16, 1), 256, 0, stream>>>(A, R1, R0, DT / 4.f, 1);
  mm256<<<dim3(16, 1), 256, 0, stream>>>(A, R0, R1, DT / 3.f, 1);
  mm256<<<dim3(16, 1), 256, 0, stream>>>(A, R1, R0, DT / 2.f, 1);
  mm256<<<dim3(16, 1), 256, 0, stream>>>(A, R0, E + 65536, DT, 1);
  // Doubling levels: E[2^j + r] = E[2^j] * E[r], r = 1..cnt
  for (int j = 0; j < 7; ++j) {
    int p   = 1 << j;
    int cnt = (TSTEPS - 1 - p < p) ? (TSTEPS - 1 - p) : p;
    mm256<<<dim3(16, cnt), 256, 0, stream>>>(E + (size_t)p * 65536, E + 65536,
                                             E + (size_t)(p + 1) * 65536, 1.f, 0);
  }

  // ---- converts to fp16 ----
  f2h<<<1024, 256, 0, stream>>>(X0, Xh);                 // 4096*256  / 1024
  f2h<<<6400, 256, 0, stream>>>(E, Wh);                  // 25600*256 / 1024

  // ---- Phase 2: big GEMM ----
  gemm_out<<<32 * 200, 256, 0, stream>>>(Xh, Wh, out);
}